// Round 8
// baseline (46858.020 us; speedup 1.0000x reference)
//
#include <hip/hip_runtime.h>
#include <hip/hip_fp16.h>
#include <cmath>

#define RN 512
#define RT 1024
#define RB 64
#define SMEM_BYTES 86016   // pad so 2 blocks can't share a CU (2*86016 > 160KB)

typedef _Float16 half2v __attribute__((ext_vector_type(2)));

__device__ __forceinline__ float fast_tanh(float x) {
    float e = __expf(2.0f * x);
    return 1.0f - 2.0f / (e + 1.0f);
}
__device__ __forceinline__ unsigned pack2(float a, float b) {
    return (unsigned)__half_as_ushort(__float2half(a)) |
           ((unsigned)__half_as_ushort(__float2half(b)) << 16);
}
__device__ __forceinline__ float dot2(unsigned wa, unsigned tb, float acc) {
    half2v a = __builtin_bit_cast(half2v, wa);
    half2v b = __builtin_bit_cast(half2v, tb);
    return __builtin_amdgcn_fdot2(a, b, acc, false);
}
// 16B-group swizzle for the input scratch: reader groups (kc*8+jj) land on
// bank-quad (jj^kc)&7 -> 8 distinct quads per read instr, row-broadcast free.
__device__ __forceinline__ int stgSwz(int g) {
    return (g & ~7) | ((g ^ (g >> 3)) & 7);
}

#define PIN4(v) asm volatile("" : "+v"((v).x), "+v"((v).y), "+v"((v).z), "+v"((v).w));

#define D2(acc, wv, tv) \
    acc = dot2((wv).x, (tv).x, acc); acc = dot2((wv).y, (tv).y, acc); \
    acc = dot2((wv).z, (tv).z, acc); acc = dot2((wv).w, (tv).w, acc);

// one-time load+pack of the lane's loop-invariant W fragment (row grow,
// k in [kc*64 + jj*8, +8)) into a named uint4, pinned to VGPRs
#define LOADW(jj, dst) { \
    const float4* _p = reinterpret_cast<const float4*>(W + (size_t)grow * RN + kc * 64 + (jj) * 8); \
    float4 _a = _p[0], _b = _p[1]; \
    dst = make_uint4(pack2(_a.x, _a.y), pack2(_a.z, _a.w), \
                     pack2(_b.x, _b.y), pack2(_b.z, _b.w)); \
    PIN4(dst) }

#define STEPJ(jj, wq) { \
    uint4 _ta = *reinterpret_cast<const uint4*>(stgA + stgSwz(kc * 8 + (jj)) * 4); \
    uint4 _tb = *reinterpret_cast<const uint4*>(stgB + stgSwz(kc * 8 + (jj)) * 4); \
    D2(aA, wq, _ta) D2(aB, wq, _tb) }

// 256 blocks x 512 threads, cooperative, 1 block/CU (LDS pad). 32 groups x 8
// same-XCD blocks (XCC_ID + arrival rank); group serves batches (g, g+32) with
// register-level W reuse. Block = part p: rows [64p, 64p+64); wave w: rows
// [64p+8w, +8); lane (rl=l>>3, kc=l&7): 1 row x 64-k chunk, W fragment in 8
// pinned uint4 VGPRs (loop-invariant!). NO barriers in the loop: each wave
// polls the group counter (acquire -> buffer_inv handles the reused exchange
// ring's L1 staleness), loads 16B/lane of each batch's packed tanh row,
// redistributes through wave-PRIVATE LDS scratch (lgkmcnt only), dots, reduces
// over the kc octet, updates h replicated, stores outH + packed exchange,
// vmcnt(0), LDS arrival count; last wave of the block bumps the group counter
// (relaxed agent, fire-and-forget; 8 bumps/group/step). ctr >= 8t guarantees
// all waves finished READING buffer (t-1)&1, making the 2-deep ring safe.
__global__ void __launch_bounds__(512, 1) rnn_step_kernel(
    const float* __restrict__ h0,
    const float* __restrict__ X,
    const float* __restrict__ W,
    const uint4* __restrict__ tanh0pk,
    float* __restrict__ outH,
    unsigned* __restrict__ exbuf,
    unsigned* __restrict__ ctr,
    unsigned* __restrict__ xcdctr)
{
    extern __shared__ unsigned char smem[];
    unsigned* stg  = (unsigned*)smem;            // 8 waves * 512 u32 (A|B)
    int*      bc   = (int*)(smem + 16384);
    unsigned* lctr = (unsigned*)(smem + 16384 + 8);

    const int tid = threadIdx.x;
    if (tid == 0) {
        unsigned xcd;
        asm volatile("s_getreg_b32 %0, hwreg(HW_REG_XCC_ID)" : "=s"(xcd));
        xcd &= 7u;
        unsigned rank = __hip_atomic_fetch_add(&xcdctr[xcd], 1u,
                            __ATOMIC_RELAXED, __HIP_MEMORY_SCOPE_AGENT) & 31u;
        int slot = (int)(xcd * 32u + rank);
        bc[0] = slot >> 3;   // group 0..31
        bc[1] = slot & 7;    // part  0..7
        *lctr = 0u;
    }
    __syncthreads();   // the ONLY block barrier (role broadcast)
    const int group = bc[0], part = bc[1];
    const int bA = group, bB = group + 32;

    const int w    = tid >> 6;
    const int l    = tid & 63;
    const int rl   = l >> 3;
    const int kc   = l & 7;
    const int grow = part * 64 + w * 8 + rl;

    uint4 w0, w1, w2, w3, w4, w5, w6, w7;
    LOADW(0, w0) LOADW(1, w1) LOADW(2, w2) LOADW(3, w3)
    LOADW(4, w4) LOADW(5, w5) LOADW(6, w6) LOADW(7, w7)

    float hA = h0[grow];
    float hB = hA;
    float xvA = X[(size_t)bA * RT * RN + grow];
    float xvB = X[(size_t)bB * RT * RN + grow];

    unsigned* gctr = ctr + group * 16;
    unsigned* stgA = stg + w * 512;
    unsigned* stgB = stgA + 256;

    #pragma unroll 1
    for (int t = 0; t < RT; ++t) {
        if (t > 0) {
            const unsigned tgt = 8u * (unsigned)t;
            while (__hip_atomic_load(gctr, __ATOMIC_ACQUIRE,
                                     __HIP_MEMORY_SCOPE_AGENT) < tgt)
                __builtin_amdgcn_s_sleep(1);
        }

        // load this wave's copy of both batches' packed tanh rows (16B/lane)
        const uint4* srcA = (t == 0) ? tanh0pk
            : reinterpret_cast<const uint4*>(exbuf + ((size_t)bA * 2 + (t & 1)) * 256);
        const uint4* srcB = (t == 0) ? tanh0pk
            : reinterpret_cast<const uint4*>(exbuf + ((size_t)bB * 2 + (t & 1)) * 256);
        uint4 va = srcA[l];
        uint4 vb = srcB[l];
        *reinterpret_cast<uint4*>(stgA + stgSwz(l) * 4) = va;
        *reinterpret_cast<uint4*>(stgB + stgSwz(l) * 4) = vb;
        asm volatile("s_waitcnt lgkmcnt(0)" ::: "memory");

        float aA = 0.f, aB = 0.f;
        STEPJ(0, w0) STEPJ(1, w1) STEPJ(2, w2) STEPJ(3, w3)
        STEPJ(4, w4) STEPJ(5, w5) STEPJ(6, w6) STEPJ(7, w7)

        // reduce over the kc octet (lane bits 0..2); acc becomes octet-uniform
        aA += __shfl_xor(aA, 1); aA += __shfl_xor(aA, 2); aA += __shfl_xor(aA, 4);
        aB += __shfl_xor(aB, 1); aB += __shfl_xor(aB, 2); aB += __shfl_xor(aB, 4);

        // h update + tanh replicated across the octet (xv loaded same-addr)
        hA = 0.9f * hA + 0.1f * (aA + xvA);
        hB = 0.9f * hB + 0.1f * (aB + xvB);
        const float thA = fast_tanh(hA);
        const float thB = fast_tanh(hB);
        const float thA1 = __shfl_xor(thA, 8);   // partner row (rl^1)
        const float thB1 = __shfl_xor(thB, 8);

        if ((l & 7) == 0) {   // kc==0: one lane per row
            outH[((size_t)bA * RT + t) * RN + grow] = thA;
            outH[((size_t)bB * RT + t) * RN + grow] = thB;
        }
        {
            unsigned* exWA = exbuf + ((size_t)bA * 2 + ((t + 1) & 1)) * 256;
            unsigned* exWB = exbuf + ((size_t)bB * 2 + ((t + 1) & 1)) * 256;
            if ((l & 15) == 0) {  // kc==0 && rl even: pack pair (row, row+1)
                const int pidx = part * 32 + w * 4 + (l >> 4);
                exWA[pidx] = pack2(thA, thA1);
                exWB[pidx] = pack2(thB, thB1);
            }
        }

        asm volatile("s_waitcnt vmcnt(0)" ::: "memory");  // ex+outH in L2
        if (l == 0) {
            unsigned a = __hip_atomic_fetch_add(lctr, 1u, __ATOMIC_RELAXED,
                                                __HIP_MEMORY_SCOPE_WORKGROUP);
            if ((a & 7u) == 7u)   // last wave of this block this step
                __hip_atomic_fetch_add(gctr, 1u, __ATOMIC_RELAXED,
                                       __HIP_MEMORY_SCOPE_AGENT);
        }

        if (t + 1 < RT) {   // prefetch next x; hides under next poll
            xvA = X[((size_t)bA * RT + (t + 1)) * RN + grow];
            xvB = X[((size_t)bB * RT + (t + 1)) * RN + grow];
        }
    }
}

// geometry epilogue: geo[b,t,:] = hidden[b,t,:] @ Gw^T + Gb ; one wave per (b,t)
__global__ void geom_kernel(const float* __restrict__ hid,
                            const float* __restrict__ Gw,
                            const float* __restrict__ Gb,
                            float* __restrict__ geo)
{
    const int wid  = (blockIdx.x * blockDim.x + threadIdx.x) >> 6;
    const int lane = threadIdx.x & 63;
    if (wid >= RB * RT) return;
    const float* rowp = hid + (size_t)wid * RN;
    float g0 = 0.f, g1 = 0.f;
    #pragma unroll
    for (int j = 0; j < 8; ++j) {
        float v = rowp[lane + 64 * j];
        g0 = fmaf(v, Gw[lane + 64 * j], g0);
        g1 = fmaf(v, Gw[RN + lane + 64 * j], g1);
    }
    #pragma unroll
    for (int m = 32; m >= 1; m >>= 1) {
        g0 += __shfl_xor(g0, m);
        g1 += __shfl_xor(g1, m);
    }
    if (lane == 0) {
        geo[(size_t)wid * 2]     = g0 + Gb[0];
        geo[(size_t)wid * 2 + 1] = g1 + Gb[1];
    }
}

// per-launch init: packed tanh(h0) row + zero counters (ws poisoned once,
// never re-poisoned -> re-init every call; deterministic)
__global__ void init_misc(const float* __restrict__ h0,
                          unsigned* __restrict__ tanh0pk,
                          unsigned* __restrict__ ctr,
                          unsigned* __restrict__ xcdctr)
{
    int i = blockIdx.x * blockDim.x + threadIdx.x;
    if (i < 256) tanh0pk[i] = pack2(tanhf(h0[2 * i]), tanhf(h0[2 * i + 1]));
    if (i < 32 * 16) ctr[i] = 0u;
    if (i < 8) xcdctr[i] = 0u;
}

extern "C" void kernel_launch(void* const* d_in, const int* in_sizes, int n_in,
                              void* d_out, int out_size, void* d_ws, size_t ws_size,
                              hipStream_t stream)
{
    const float* h0 = (const float*)d_in[0];
    const float* X  = (const float*)d_in[1];
    const float* W  = (const float*)d_in[2];
    const float* Gw = (const float*)d_in[3];
    const float* Gb = (const float*)d_in[4];

    float* outH = (float*)d_out;
    float* geo  = outH + (size_t)RB * RT * RN;

    unsigned* exbuf   = (unsigned*)d_ws;            // 64*2*256 u32 = 128 KB
    unsigned* tanh0pk = exbuf + 64 * 2 * 256;       // 256 u32
    unsigned* ctr     = tanh0pk + 256;              // 32*16 u32
    unsigned* xcdctr  = ctr + 32 * 16;              // 8 u32

    (void)hipFuncSetAttribute((const void*)rnn_step_kernel,
                              hipFuncAttributeMaxDynamicSharedMemorySize, SMEM_BYTES);

    init_misc<<<1, 512, 0, stream>>>(h0, tanh0pk, ctr, xcdctr);

    void* kargs[] = { (void*)&h0, (void*)&X, (void*)&W, (void*)&tanh0pk,
                      (void*)&outH, (void*)&exbuf, (void*)&ctr, (void*)&xcdctr };
    hipLaunchCooperativeKernel(rnn_step_kernel, dim3(256), dim3(512),
                               kargs, SMEM_BYTES, stream);

    geom_kernel<<<(RB * RT * 64 + 255) / 256, 256, 0, stream>>>(outH, Gw, Gb, geo);
}

// Round 10
// 8727.784 us; speedup vs baseline: 5.3688x; 5.3688x over previous
//
#include <hip/hip_runtime.h>
#include <cmath>

#define RN 512
#define RT 1024
#define RB 64
#define SMEM_BYTES (131072 + 32)   // 128KB W + ctl; 2x > 160KB -> 1 block/CU

typedef float f32x2 __attribute__((ext_vector_type(2)));

__device__ __forceinline__ float fast_tanh(float x) {
    float e = __expf(2.0f * x);
    return 1.0f - 2.0f / (e + 1.0f);
}

// two dual-fp32 packed FMAs: acc += wv * vv (element-wise over a float4)
#define PKFMA2(acc, wv, vv) { \
    f32x2 _w0 = { (wv).x, (wv).y }, _w1 = { (wv).z, (wv).w }; \
    f32x2 _v0 = { (vv).x, (vv).y }, _v1 = { (vv).z, (vv).w }; \
    asm("v_pk_fma_f32 %0, %1, %2, %0" : "+v"(acc) : "v"(_w0), "v"(_v0)); \
    asm("v_pk_fma_f32 %0, %1, %2, %0" : "+v"(acc) : "v"(_w1), "v"(_v1)); }

// 256 blocks x 512 threads, cooperative, 1 block/CU (LDS pad). 32 groups x 8
// same-XCD blocks (XCC_ID + arrival rank); group serves batches (g, g+32),
// sharing one W pass. Block = part p (rows [64p,+64)); wave w owns rows
// [64p+8w,+8) end-to-end; lane (rl=l>>3, kc=l&7) = 1 row x 64-k chunk.
// W fp32 in LDS in exact read order [w][j][lane] -> full-throughput
// ds_read_b128. NO barriers / NO acquires in the loop (agent-acquire = L1+L2
// invalidate = round-8 disaster). Exchange = outH itself: producer's fp32
// store IS the exchange; readers load the previous row directly -- every
// exchange address is FIRST-TOUCH for the reading CU within a launch, so L1
// staleness cannot occur (round-9's reused-ring lesson), and cross-replay
// retention is benign (deterministic values). Visibility: stores ->
// s_waitcnt vmcnt(0) -> LDS arrival counter; 8th wave bumps the group
// counter (relaxed agent, atomics act at the shared XCD L2); consumers poll
// relaxed. Ring-free, so no slot-reuse hazard at all.
__global__ void __launch_bounds__(512, 1) rnn_step_kernel(
    const float* __restrict__ h0,
    const float* __restrict__ X,
    const float* __restrict__ W,
    const float* __restrict__ tanh0,
    float* __restrict__ outH,
    unsigned* __restrict__ ctr,
    unsigned* __restrict__ xcdctr)
{
    extern __shared__ unsigned char smem[];
    float4*   Wl   = (float4*)smem;                  // [8 w][16 j][64 l]
    int*      bc   = (int*)(smem + 131072);
    unsigned* lctr = (unsigned*)(smem + 131072 + 8);

    const int tid = threadIdx.x;
    if (tid == 0) {
        unsigned xcd;
        asm volatile("s_getreg_b32 %0, hwreg(HW_REG_XCC_ID)" : "=s"(xcd));
        xcd &= 7u;
        unsigned rank = __hip_atomic_fetch_add(&xcdctr[xcd], 1u,
                            __ATOMIC_RELAXED, __HIP_MEMORY_SCOPE_AGENT) & 31u;
        int slot = (int)(xcd * 32u + rank);
        bc[0] = slot >> 3;   // group 0..31
        bc[1] = slot & 7;    // part  0..7
        *lctr = 0u;
    }
    __syncthreads();
    const int group = bc[0], part = bc[1];
    const int bA = group, bB = group + 32;

    // stage W slice (fp32) into read-order layout:
    // slot (w*16+j)*64+l  <-  W[part*64 + w*8 + (l>>3)][(l&7)*64 + 4j .. +3]
    for (int s = tid; s < 8192; s += 512) {
        int w_ = s >> 10, j = (s >> 6) & 15, l_ = s & 63;
        int row = part * 64 + w_ * 8 + (l_ >> 3);
        int col = (l_ & 7) * 64 + j * 4;
        Wl[s] = *reinterpret_cast<const float4*>(W + (size_t)row * RN + col);
    }

    const int w = tid >> 6, l = tid & 63;
    const int rl = l >> 3, kc = l & 7;
    const int grow = part * 64 + w * 8 + rl;

    float hA = h0[grow], hB = hA;
    float xvA = X[(size_t)bA * RT * RN + grow];
    float xvB = X[(size_t)bB * RT * RN + grow];

    unsigned* gctr = ctr + group * 32;        // 128B line per group
    const float4* wbase = Wl + w * 1024 + l;  // + j*64

    __syncthreads();   // W staged (last barrier)

    #pragma unroll 1
    for (int t = 0; t < RT; ++t) {
        if (t > 0) {
            if (l == 0) {
                const unsigned tgt = 8u * (unsigned)t;
                while (__hip_atomic_load(gctr, __ATOMIC_RELAXED,
                                         __HIP_MEMORY_SCOPE_AGENT) < tgt)
                    __builtin_amdgcn_s_sleep(1);
            }
            __builtin_amdgcn_sched_barrier(0);   // nothing hoists above the gate
            asm volatile("" ::: "memory");
        }

        // previous tanh row (or tanh0 at t=0): this lane's 256B k-chunk.
        // first-touch addresses for this CU -> plain loads are L2-fresh.
        const float* srcA = (t == 0) ? tanh0
            : (outH + ((size_t)bA * RT + (t - 1)) * RN);
        const float* srcB = (t == 0) ? tanh0
            : (outH + ((size_t)bB * RT + (t - 1)) * RN);
        const float4* pA = reinterpret_cast<const float4*>(srcA + kc * 64);
        const float4* pB = reinterpret_cast<const float4*>(srcB + kc * 64);

        f32x2 accA = {0.f, 0.f}, accB = {0.f, 0.f};
        #pragma unroll
        for (int j = 0; j < 16; ++j) {
            float4 wv = wbase[j * 64];   // ds_read_b128, conflict-free pattern
            float4 va = pA[j];
            float4 vb = pB[j];
            PKFMA2(accA, wv, va)
            PKFMA2(accB, wv, vb)
        }
        float aA = accA.x + accA.y;
        float aB = accB.x + accB.y;

        // reduce over the kc octet (lane bits 0..2); result octet-uniform
        aA += __shfl_xor(aA, 1); aA += __shfl_xor(aA, 2); aA += __shfl_xor(aA, 4);
        aB += __shfl_xor(aB, 1); aB += __shfl_xor(aB, 2); aB += __shfl_xor(aB, 4);

        hA = 0.9f * hA + 0.1f * (aA + xvA);
        hB = 0.9f * hB + 0.1f * (aB + xvB);
        const float thA = fast_tanh(hA), thB = fast_tanh(hB);

        if (kc == 0) {   // one lane per row stores both batches' outputs
            outH[((size_t)bA * RT + t) * RN + grow] = thA;
            outH[((size_t)bB * RT + t) * RN + grow] = thB;
        }
        asm volatile("s_waitcnt vmcnt(0)" ::: "memory");   // stores in XCD L2
        if (l == 0) {
            unsigned a = __hip_atomic_fetch_add(lctr, 1u, __ATOMIC_RELAXED,
                                                __HIP_MEMORY_SCOPE_WORKGROUP);
            if ((a & 7u) == 7u)   // 8th wave of this block this step
                __hip_atomic_fetch_add(gctr, 1u, __ATOMIC_RELAXED,
                                       __HIP_MEMORY_SCOPE_AGENT);
        }

        if (t + 1 < RT) {   // off-chain: next-x prefetch hides under next poll
            xvA = X[((size_t)bA * RT + (t + 1)) * RN + grow];
            xvB = X[((size_t)bB * RT + (t + 1)) * RN + grow];
        }
    }
}

// geometry epilogue: geo[b,t,:] = hidden[b,t,:] @ Gw^T + Gb ; one wave per (b,t)
__global__ void geom_kernel(const float* __restrict__ hid,
                            const float* __restrict__ Gw,
                            const float* __restrict__ Gb,
                            float* __restrict__ geo)
{
    const int wid  = (blockIdx.x * blockDim.x + threadIdx.x) >> 6;
    const int lane = threadIdx.x & 63;
    if (wid >= RB * RT) return;
    const float* rowp = hid + (size_t)wid * RN;
    float g0 = 0.f, g1 = 0.f;
    #pragma unroll
    for (int j = 0; j < 8; ++j) {
        float v = rowp[lane + 64 * j];
        g0 = fmaf(v, Gw[lane + 64 * j], g0);
        g1 = fmaf(v, Gw[RN + lane + 64 * j], g1);
    }
    #pragma unroll
    for (int m = 32; m >= 1; m >>= 1) {
        g0 += __shfl_xor(g0, m);
        g1 += __shfl_xor(g1, m);
    }
    if (lane == 0) {
        geo[(size_t)wid * 2]     = g0 + Gb[0];
        geo[(size_t)wid * 2 + 1] = g1 + Gb[1];
    }
}

// per-launch init: tanh(h0) fp32 table + zero counters (ws poisoned once,
// never re-poisoned -> re-init every call; deterministic)
__global__ void init_misc(const float* __restrict__ h0,
                          float* __restrict__ tanh0,
                          unsigned* __restrict__ ctr,
                          unsigned* __restrict__ xcdctr)
{
    int i = blockIdx.x * blockDim.x + threadIdx.x;
    if (i < RN) tanh0[i] = tanhf(h0[i]);
    if (i < 32 * 32) ctr[i] = 0u;
    if (i < 8) xcdctr[i] = 0u;
}

extern "C" void kernel_launch(void* const* d_in, const int* in_sizes, int n_in,
                              void* d_out, int out_size, void* d_ws, size_t ws_size,
                              hipStream_t stream)
{
    const float* h0 = (const float*)d_in[0];
    const float* X  = (const float*)d_in[1];
    const float* W  = (const float*)d_in[2];
    const float* Gw = (const float*)d_in[3];
    const float* Gb = (const float*)d_in[4];

    float* outH = (float*)d_out;
    float* geo  = outH + (size_t)RB * RT * RN;

    float*    tanh0  = (float*)d_ws;            // 512 f32
    unsigned* ctr    = (unsigned*)d_ws + RN;    // 32*32 u32
    unsigned* xcdctr = ctr + 32 * 32;           // 8 u32

    (void)hipFuncSetAttribute((const void*)rnn_step_kernel,
                              hipFuncAttributeMaxDynamicSharedMemorySize, SMEM_BYTES);

    init_misc<<<4, 512, 0, stream>>>(h0, tanh0, ctr, xcdctr);

    void* kargs[] = { (void*)&h0, (void*)&X, (void*)&W, (void*)&tanh0,
                      (void*)&outH, (void*)&ctr, (void*)&xcdctr };
    hipLaunchCooperativeKernel(rnn_step_kernel, dim3(256), dim3(512),
                               kargs, SMEM_BYTES, stream);

    geom_kernel<<<(RB * RT * 64 + 255) / 256, 256, 0, stream>>>(outH, Gw, Gb, geo);
}

// Round 13
// 2078.325 us; speedup vs baseline: 22.5461x; 4.1994x over previous
//
#include <hip/hip_runtime.h>
#include <hip/hip_fp16.h>
#include <cmath>

#define RN 512
#define RT 1024
#define RB 64
#define SMEM_BYTES (131072 + 320)   // 128KB W + ownpk(256B) + ctl; 2x > 160KB -> 1 block/CU

typedef _Float16 half2v __attribute__((ext_vector_type(2)));

__device__ __forceinline__ float fast_tanh(float x) {
    float e = __expf(2.0f * x);
    return 1.0f - 2.0f / (e + 1.0f);
}
__device__ __forceinline__ unsigned pack2(float a, float b) {   // RNE
    return (unsigned)__half_as_ushort(__float2half(a)) |
           ((unsigned)__half_as_ushort(__float2half(b)) << 16);
}
__device__ __forceinline__ unsigned pkrtz(float a, float b) {   // 1-instr pack
    auto h = __builtin_amdgcn_cvt_pkrtz(a, b);   // __fp16 ext_vector(2)
    return __builtin_bit_cast(unsigned, h);
}
__device__ __forceinline__ float dot2(unsigned wa, unsigned tb, float acc) {
    half2v a = __builtin_bit_cast(half2v, wa);
    half2v b = __builtin_bit_cast(half2v, tb);
    return __builtin_amdgcn_fdot2(a, b, acc, false);
}
#define D2Q(acc, wq, tq) \
    acc = dot2((wq).x, (tq).x, acc); acc = dot2((wq).y, (tq).y, acc); \
    acc = dot2((wq).z, (tq).z, acc); acc = dot2((wq).w, (tq).w, acc);

// 256 blocks x 512 threads, cooperative, 1 block/CU (LDS pad). R6-PROVEN
// geometry: slot = xcd*32 + arrival-rank -> batch = slot>>2 (0..63), part =
// slot&3 (0..3) -- every index in range by construction (round-12 lesson:
// the 2-batch "group" variant computed group in [0,64) and wrote OOB).
// One batch per same-XCD quad; block owns rows [128p, +128); W slice f16 in
// LDS pre-permuted by pack_w into EXACT read order [band][i][tid] ->
// lane-consecutive ds_read_b128, zero conflicts by construction (R10-proven).
// Thread (rg=tid>>4: 4 rows, kc=tid&15: 8-k subchunk per band). Per step:
// phase A (own band, tanh from the ownpk LDS pair-buffer -- no partner
// dependency) runs BEFORE the poll, filling the wait window; tid0 polls the
// quad counter (RELAXED agent -- NO acquire, round-8's 18x disaster), one
// barrier broadcasts; phase B reads the 3 partner bands fp32 directly from
// outH (FRESH addresses every step -> no L1 staleness; the only exchange
// channel that has ever passed) into registers, pkrtz-packed -- no staging.
// Bottom barrier drains all waves' stores (vmcnt 0 before s_barrier) before
// tid0 signals. 2 barriers/step total.
__global__ void __launch_bounds__(512, 1) rnn_step_kernel(
    const float* __restrict__ h0,
    const float* __restrict__ X,
    const uint4* __restrict__ Wpk,     // [4 part][4 band][4 i][512 tid]
    const float* __restrict__ tanh0,
    float* __restrict__ outH,
    unsigned* __restrict__ ctr,
    unsigned* __restrict__ xcdctr)
{
    extern __shared__ unsigned char smem[];
    uint4*    Wl    = (uint4*)smem;                  // 8192 uint4 = 128 KB
    unsigned* ownpk = (unsigned*)(smem + 131072);    // 64 u32 pairs (own rows)
    int*      bc    = (int*)(smem + 131072 + 256);

    const int tid = threadIdx.x;
    if (tid == 0) {
        unsigned xcd;
        asm volatile("s_getreg_b32 %0, hwreg(HW_REG_XCC_ID)" : "=s"(xcd));
        xcd &= 7u;
        unsigned rank = __hip_atomic_fetch_add(&xcdctr[xcd], 1u,
                            __ATOMIC_RELAXED, __HIP_MEMORY_SCOPE_AGENT) & 31u;
        int slot = (int)(xcd * 32u + rank);   // 0..255
        bc[0] = slot >> 2;                    // batch 0..63
        bc[1] = slot & 3;                     // part  0..3
    }
    __syncthreads();
    const int batch = bc[0], part = bc[1];

    // stage our part's W slice (pre-permuted read order): straight copy
    {
        const uint4* src = Wpk + part * 8192;
        #pragma unroll
        for (int i = 0; i < 16; ++i)
            Wl[i * 512 + tid] = src[i * 512 + tid];
    }

    const int rg = tid >> 4;                  // 0..31 : 4-row group
    const int kc = tid & 15;                  // 0..15 : 8-k sub-chunk per band
    const int row0 = part * 128 + rg * 4;     // first global row of this thread

    // h state lives on kc==0 threads (4 rows)
    float4 h = {0, 0, 0, 0};
    if (kc == 0) {
        h = *reinterpret_cast<const float4*>(h0 + row0);
        float t0 = tanhf(h.x), t1 = tanhf(h.y), t2 = tanhf(h.z), t3 = tanhf(h.w);
        ownpk[2 * rg]     = pack2(t0, t1);    // pairs cover own rows only
        ownpk[2 * rg + 1] = pack2(t2, t3);
    }

    unsigned* gctr = ctr + batch * 32;        // 128B line per quad
    __syncthreads();                          // W + ownpk staged

    #pragma unroll 1
    for (int t = 0; t < RT; ++t) {
        // ---- phase A: own band (b = part) -- zero partner dependency ----
        float acc0 = 0.f, acc1 = 0.f, acc2 = 0.f, acc3 = 0.f;
        {
            uint4 th = *reinterpret_cast<const uint4*>(&ownpk[4 * kc]);
            uint4 wq0 = Wl[(part * 4 + 0) * 512 + tid];
            uint4 wq1 = Wl[(part * 4 + 1) * 512 + tid];
            uint4 wq2 = Wl[(part * 4 + 2) * 512 + tid];
            uint4 wq3 = Wl[(part * 4 + 3) * 512 + tid];
            D2Q(acc0, wq0, th) D2Q(acc1, wq1, th)
            D2Q(acc2, wq2, th) D2Q(acc3, wq3, th)
        }
        // x for this step (kc==0 only); issued early, hides under poll
        float4 xv = {0, 0, 0, 0};
        if (kc == 0)
            xv = *reinterpret_cast<const float4*>(&X[((size_t)batch * RT + t) * RN + row0]);

        // ---- wait for all 4 parts of step t-1 (tid0 poll + barrier bcast) ----
        if (tid == 0 && t > 0) {
            const unsigned tgt = 4u * (unsigned)t;
            while (__hip_atomic_load(gctr, __ATOMIC_RELAXED,
                                     __HIP_MEMORY_SCOPE_AGENT) < tgt)
                __builtin_amdgcn_s_sleep(1);
        }
        __syncthreads();

        // ---- phase B: 3 partner bands, fp32 outH -> registers -> pkrtz ----
        const float* srcR = (t == 0) ? tanh0
            : &outH[((size_t)batch * RT + (t - 1)) * RN];
        #pragma unroll
        for (int bb = 0; bb < 3; ++bb) {
            const int b = bb + (bb >= part);
            const int ko = b * 128 + kc * 8;
            float4 f0 = *reinterpret_cast<const float4*>(srcR + ko);
            float4 f1 = *reinterpret_cast<const float4*>(srcR + ko + 4);
            uint4 tv = make_uint4(pkrtz(f0.x, f0.y), pkrtz(f0.z, f0.w),
                                  pkrtz(f1.x, f1.y), pkrtz(f1.z, f1.w));
            uint4 wq0 = Wl[(b * 4 + 0) * 512 + tid];
            uint4 wq1 = Wl[(b * 4 + 1) * 512 + tid];
            uint4 wq2 = Wl[(b * 4 + 2) * 512 + tid];
            uint4 wq3 = Wl[(b * 4 + 3) * 512 + tid];
            D2Q(acc0, wq0, tv) D2Q(acc1, wq1, tv)
            D2Q(acc2, wq2, tv) D2Q(acc3, wq3, tv)
        }

        // reduce over the 16 kc lanes (tid bits 0..3, stays in-wave)
        #pragma unroll
        for (int m = 1; m <= 8; m <<= 1) {
            acc0 += __shfl_xor(acc0, m);
            acc1 += __shfl_xor(acc1, m);
            acc2 += __shfl_xor(acc2, m);
            acc3 += __shfl_xor(acc3, m);
        }

        if (kc == 0) {
            h.x = 0.9f * h.x + 0.1f * (acc0 + xv.x);
            h.y = 0.9f * h.y + 0.1f * (acc1 + xv.y);
            h.z = 0.9f * h.z + 0.1f * (acc2 + xv.z);
            h.w = 0.9f * h.w + 0.1f * (acc3 + xv.w);
            float t0 = fast_tanh(h.x), t1 = fast_tanh(h.y);
            float t2 = fast_tanh(h.z), t3 = fast_tanh(h.w);
            *reinterpret_cast<float4*>(&outH[((size_t)batch * RT + t) * RN + row0]) =
                make_float4(t0, t1, t2, t3);
            // stage own tanh pairs for next step's phase A
            ownpk[2 * rg]     = pack2(t0, t1);
            ownpk[2 * rg + 1] = pack2(t2, t3);
        }

        __syncthreads();   // every wave drains vmcnt(0)+lgkm before s_barrier
        if (tid == 0)      // -> all stores in XCD L2 before the signal
            __hip_atomic_fetch_add(gctr, 1u, __ATOMIC_RELAXED,
                                   __HIP_MEMORY_SCOPE_AGENT);
    }
}

// one-time: W -> f16 pairs in exact per-read order
// Wpk[part*8192 + (b*4+i)*512 + tid] = W[part*128+(tid>>4)*4+i][b*128+(tid&15)*8 ..+8]
__global__ void pack_w(const float* __restrict__ W, uint4* __restrict__ Wpk)
{
    int o = blockIdx.x * blockDim.x + threadIdx.x;
    if (o >= 32768) return;
    int part = o >> 13;
    int b    = (o >> 11) & 3;
    int i    = (o >> 9) & 3;
    int tid  = o & 511;
    int row  = part * 128 + (tid >> 4) * 4 + i;
    int k0   = b * 128 + (tid & 15) * 8;
    const float* s = W + (size_t)row * RN + k0;
    uint4 v;
    v.x = pack2(s[0], s[1]); v.y = pack2(s[2], s[3]);
    v.z = pack2(s[4], s[5]); v.w = pack2(s[6], s[7]);
    Wpk[o] = v;
}

// geometry epilogue: geo[b,t,:] = hidden[b,t,:] @ Gw^T + Gb ; one wave per (b,t)
__global__ void geom_kernel(const float* __restrict__ hid,
                            const float* __restrict__ Gw,
                            const float* __restrict__ Gb,
                            float* __restrict__ geo)
{
    const int wid  = (blockIdx.x * blockDim.x + threadIdx.x) >> 6;
    const int lane = threadIdx.x & 63;
    if (wid >= RB * RT) return;
    const float* rowp = hid + (size_t)wid * RN;
    float g0 = 0.f, g1 = 0.f;
    #pragma unroll
    for (int j = 0; j < 8; ++j) {
        float v = rowp[lane + 64 * j];
        g0 = fmaf(v, Gw[lane + 64 * j], g0);
        g1 = fmaf(v, Gw[RN + lane + 64 * j], g1);
    }
    #pragma unroll
    for (int m = 32; m >= 1; m >>= 1) {
        g0 += __shfl_xor(g0, m);
        g1 += __shfl_xor(g1, m);
    }
    if (lane == 0) {
        geo[(size_t)wid * 2]     = g0 + Gb[0];
        geo[(size_t)wid * 2 + 1] = g1 + Gb[1];
    }
}

// per-launch init: tanh(h0) table + zero counters (ws poisoned once, never
// re-poisoned -> re-init every call; deterministic)
__global__ void init_misc(const float* __restrict__ h0,
                          float* __restrict__ tanh0,
                          unsigned* __restrict__ ctr,
                          unsigned* __restrict__ xcdctr)
{
    int i = blockIdx.x * blockDim.x + threadIdx.x;
    if (i < RN) tanh0[i] = tanhf(h0[i]);
    if (i < RB * 32) ctr[i] = 0u;
    if (i < 8) xcdctr[i] = 0u;
}

extern "C" void kernel_launch(void* const* d_in, const int* in_sizes, int n_in,
                              void* d_out, int out_size, void* d_ws, size_t ws_size,
                              hipStream_t stream)
{
    const float* h0 = (const float*)d_in[0];
    const float* X  = (const float*)d_in[1];
    const float* W  = (const float*)d_in[2];
    const float* Gw = (const float*)d_in[3];
    const float* Gb = (const float*)d_in[4];

    float* outH = (float*)d_out;
    float* geo  = outH + (size_t)RB * RT * RN;

    float*    tanh0  = (float*)d_ws;                  // 512 f32
    unsigned* ctr    = (unsigned*)d_ws + RN;          // 64*32 u32
    unsigned* xcdctr = ctr + RB * 32;                 // 8 u32
    uint4*    Wpk    = (uint4*)(((uintptr_t)(xcdctr + 8) + 15) & ~(uintptr_t)15);

    (void)hipFuncSetAttribute((const void*)rnn_step_kernel,
                              hipFuncAttributeMaxDynamicSharedMemorySize, SMEM_BYTES);

    pack_w<<<64, 512, 0, stream>>>(W, Wpk);
    init_misc<<<8, 512, 0, stream>>>(h0, tanh0, ctr, xcdctr);

    void* kargs[] = { (void*)&h0, (void*)&X, (void*)&Wpk, (void*)&tanh0,
                      (void*)&outH, (void*)&ctr, (void*)&xcdctr };
    (void)hipLaunchCooperativeKernel(rnn_step_kernel, dim3(256), dim3(512),
                                     kargs, SMEM_BYTES, stream);

    geom_kernel<<<(RB * RT * 64 + 255) / 256, 256, 0, stream>>>(outH, Gw, Gb, geo);
}

// Round 15
// 2034.320 us; speedup vs baseline: 23.0337x; 1.0216x over previous
//
#include <hip/hip_runtime.h>
#include <hip/hip_fp16.h>
#include <cmath>

#define RN 512
#define RT 1024
#define RB 64
#define SMEM_BYTES (131072 + 320)   // 128KB W + ownpk(256B) + ctl; 2x > 160KB -> 1 block/CU

typedef _Float16 half2v __attribute__((ext_vector_type(2)));

__device__ __forceinline__ float fast_tanh(float x) {
    float e = __expf(2.0f * x);
    return 1.0f - 2.0f / (e + 1.0f);
}
__device__ __forceinline__ unsigned pack2(float a, float b) {   // RNE
    return (unsigned)__half_as_ushort(__float2half(a)) |
           ((unsigned)__half_as_ushort(__float2half(b)) << 16);
}
__device__ __forceinline__ unsigned pkrtz(float a, float b) {   // 1-instr pack
    auto h = __builtin_amdgcn_cvt_pkrtz(a, b);
    return __builtin_bit_cast(unsigned, h);
}
__device__ __forceinline__ float dot2(unsigned wa, unsigned tb, float acc) {
    half2v a = __builtin_bit_cast(half2v, wa);
    half2v b = __builtin_bit_cast(half2v, tb);
    return __builtin_amdgcn_fdot2(a, b, acc, false);
}
// VALU cross-lane add via DPP (no LDS pipe). ctrl must be an ICE -> template.
template <int CTRL>
__device__ __forceinline__ float dpp_add(float x) {
    int p = __builtin_amdgcn_update_dpp(0, __float_as_int(x), CTRL, 0xf, 0xf, true);
    return x + __int_as_float(p);
}
__device__ __forceinline__ float red16(float x) {
    x = dpp_add<0xB1>(x);   // quad_perm [1,0,3,2]  : xor1
    x = dpp_add<0x4E>(x);   // quad_perm [2,3,0,1]  : xor2
    x = dpp_add<0x141>(x);  // row_half_mirror      : pairs quads 0-1 / 2-3
    x = dpp_add<0x140>(x);  // row_mirror           : pairs halves
    return x;
}
#define D2Q(acc, wq, tq) \
    acc = dot2((wq).x, (tq).x, acc); acc = dot2((wq).y, (tq).y, acc); \
    acc = dot2((wq).z, (tq).z, acc); acc = dot2((wq).w, (tq).w, acc);

// R13 skeleton (proven: 2078us, 0 conflicts): 256 blocks x 512 threads,
// cooperative, 1 block/CU. slot = xcd*32+rank -> batch = slot>>2, part =
// slot&3 (in-range by construction). W slice f16 LDS, pre-permuted read order
// [band][i][tid] -> conflict-free ds_read_b128. Phase A (own band via ownpk)
// before the poll; tid0 polls RELAXED agent counter; phase B reads partner
// bands fp32 from outH (fresh addresses = the only proven exchange channel).
// Round-14 deltas: (1) X[t+1] prefetch issued at the TOP of step t (full-step
// window hides ~900cy HBM latency that previously sat on the chain);
// (2) 16-lane reduce via DPP VALU adds (frees LDS pipe, ~4x fewer xlane ops);
// (3) signal hoisted before the bottom barrier: each wave drains vmcnt(0),
// bumps an LDS arrival counter, 8th wave fires the global signal -- partners
// stop waiting on our intra-block rendezvous.
__global__ void __launch_bounds__(512, 1) rnn_step_kernel(
    const float* __restrict__ h0,
    const float* __restrict__ X,
    const uint4* __restrict__ Wpk,     // [4 part][4 band][4 i][512 tid]
    const float* __restrict__ tanh0,
    float* __restrict__ outH,
    unsigned* __restrict__ ctr,
    unsigned* __restrict__ xcdctr)
{
    extern __shared__ unsigned char smem[];
    uint4*    Wl    = (uint4*)smem;                  // 8192 uint4 = 128 KB
    unsigned* ownpk = (unsigned*)(smem + 131072);    // 64 u32 pairs (own rows)
    int*      bc    = (int*)(smem + 131072 + 256);
    unsigned* lctr  = (unsigned*)(smem + 131072 + 264);

    const int tid = threadIdx.x;
    if (tid == 0) {
        unsigned xcd;
        asm volatile("s_getreg_b32 %0, hwreg(HW_REG_XCC_ID)" : "=s"(xcd));
        xcd &= 7u;
        unsigned rank = __hip_atomic_fetch_add(&xcdctr[xcd], 1u,
                            __ATOMIC_RELAXED, __HIP_MEMORY_SCOPE_AGENT) & 31u;
        int slot = (int)(xcd * 32u + rank);   // 0..255
        bc[0] = slot >> 2;                    // batch 0..63
        bc[1] = slot & 3;                     // part  0..3
        *lctr = 0u;
    }
    __syncthreads();
    const int batch = bc[0], part = bc[1];

    // stage our part's W slice (pre-permuted read order): straight copy
    {
        const uint4* src = Wpk + part * 8192;
        #pragma unroll
        for (int i = 0; i < 16; ++i)
            Wl[i * 512 + tid] = src[i * 512 + tid];
    }

    const int rg = tid >> 4;                  // 0..31 : 4-row group
    const int kc = tid & 15;                  // 0..15 : 8-k sub-chunk per band
    const int row0 = part * 128 + rg * 4;

    float4 h = {0, 0, 0, 0};
    float4 xv = {0, 0, 0, 0};
    if (kc == 0) {
        h = *reinterpret_cast<const float4*>(h0 + row0);
        float t0 = tanhf(h.x), t1 = tanhf(h.y), t2 = tanhf(h.z), t3 = tanhf(h.w);
        ownpk[2 * rg]     = pack2(t0, t1);
        ownpk[2 * rg + 1] = pack2(t2, t3);
        xv = *reinterpret_cast<const float4*>(&X[(size_t)batch * RT * RN + row0]);
    }

    unsigned* gctr = ctr + batch * 32;        // 128B line per quad
    __syncthreads();                          // W + ownpk staged

    #pragma unroll 1
    for (int t = 0; t < RT; ++t) {
        // ---- 2-deep X prefetch: issue X[t+1] now, consume next iteration ----
        float4 xn = {0, 0, 0, 0};
        if (kc == 0) {
            const int tn = (t + 1 < RT) ? t + 1 : t;
            xn = *reinterpret_cast<const float4*>(&X[((size_t)batch * RT + tn) * RN + row0]);
        }

        // ---- phase A: own band (b = part) -- zero partner dependency ----
        float acc0 = 0.f, acc1 = 0.f, acc2 = 0.f, acc3 = 0.f;
        {
            uint4 th = *reinterpret_cast<const uint4*>(&ownpk[4 * kc]);
            uint4 wq0 = Wl[(part * 4 + 0) * 512 + tid];
            uint4 wq1 = Wl[(part * 4 + 1) * 512 + tid];
            uint4 wq2 = Wl[(part * 4 + 2) * 512 + tid];
            uint4 wq3 = Wl[(part * 4 + 3) * 512 + tid];
            D2Q(acc0, wq0, th) D2Q(acc1, wq1, th)
            D2Q(acc2, wq2, th) D2Q(acc3, wq3, th)
        }

        // ---- wait for all 4 parts of step t-1 (tid0 poll + barrier bcast) ----
        if (tid == 0 && t > 0) {
            const unsigned tgt = 4u * (unsigned)t;
            while (__hip_atomic_load(gctr, __ATOMIC_RELAXED,
                                     __HIP_MEMORY_SCOPE_AGENT) < tgt)
                __builtin_amdgcn_s_sleep(1);
        }
        __syncthreads();

        // ---- phase B: 3 partner bands, fp32 outH -> registers -> pkrtz ----
        const float* srcR = (t == 0) ? tanh0
            : &outH[((size_t)batch * RT + (t - 1)) * RN];
        #pragma unroll
        for (int bb = 0; bb < 3; ++bb) {
            const int b = bb + (bb >= part);
            const int ko = b * 128 + kc * 8;
            float4 f0 = *reinterpret_cast<const float4*>(srcR + ko);
            float4 f1 = *reinterpret_cast<const float4*>(srcR + ko + 4);
            uint4 tv = make_uint4(pkrtz(f0.x, f0.y), pkrtz(f0.z, f0.w),
                                  pkrtz(f1.x, f1.y), pkrtz(f1.z, f1.w));
            uint4 wq0 = Wl[(b * 4 + 0) * 512 + tid];
            uint4 wq1 = Wl[(b * 4 + 1) * 512 + tid];
            uint4 wq2 = Wl[(b * 4 + 2) * 512 + tid];
            uint4 wq3 = Wl[(b * 4 + 3) * 512 + tid];
            D2Q(acc0, wq0, tv) D2Q(acc1, wq1, tv)
            D2Q(acc2, wq2, tv) D2Q(acc3, wq3, tv)
        }

        // ---- 16-lane all-reduce entirely in VALU (DPP), no LDS pipe ----
        acc0 = red16(acc0); acc1 = red16(acc1);
        acc2 = red16(acc2); acc3 = red16(acc3);

        if (kc == 0) {
            h.x = 0.9f * h.x + 0.1f * (acc0 + xv.x);
            h.y = 0.9f * h.y + 0.1f * (acc1 + xv.y);
            h.z = 0.9f * h.z + 0.1f * (acc2 + xv.z);
            h.w = 0.9f * h.w + 0.1f * (acc3 + xv.w);
            float t0 = fast_tanh(h.x), t1 = fast_tanh(h.y);
            float t2 = fast_tanh(h.z), t3 = fast_tanh(h.w);
            *reinterpret_cast<float4*>(&outH[((size_t)batch * RT + t) * RN + row0]) =
                make_float4(t0, t1, t2, t3);
            ownpk[2 * rg]     = pack2(t0, t1);
            ownpk[2 * rg + 1] = pack2(t2, t3);
        }

        // ---- signal hoist: per-wave drain -> LDS arrival -> 8th wave fires ----
        asm volatile("s_waitcnt vmcnt(0)" ::: "memory");   // this wave's stores in L2
        if ((tid & 63) == 0) {
            unsigned a = __hip_atomic_fetch_add(lctr, 1u, __ATOMIC_RELAXED,
                                                __HIP_MEMORY_SCOPE_WORKGROUP);
            if ((a & 7u) == 7u)   // 8th wave this step: all stores drained
                __hip_atomic_fetch_add(gctr, 1u, __ATOMIC_RELAXED,
                                       __HIP_MEMORY_SCOPE_AGENT);
        }
        __syncthreads();   // ownpk coherence for next step's phase A
        xv = xn;
    }
}

// one-time: W -> f16 pairs in exact per-read order
// Wpk[part*8192 + (b*4+i)*512 + tid] = W[part*128+(tid>>4)*4+i][b*128+(tid&15)*8 ..+8]
__global__ void pack_w(const float* __restrict__ W, uint4* __restrict__ Wpk)
{
    int o = blockIdx.x * blockDim.x + threadIdx.x;
    if (o >= 32768) return;
    int part = o >> 13;
    int b    = (o >> 11) & 3;
    int i    = (o >> 9) & 3;
    int tid  = o & 511;
    int row  = part * 128 + (tid >> 4) * 4 + i;
    int k0   = b * 128 + (tid & 15) * 8;
    const float* s = W + (size_t)row * RN + k0;
    uint4 v;
    v.x = pack2(s[0], s[1]); v.y = pack2(s[2], s[3]);
    v.z = pack2(s[4], s[5]); v.w = pack2(s[6], s[7]);
    Wpk[o] = v;
}

// geometry epilogue: geo[b,t,:] = hidden[b,t,:] @ Gw^T + Gb ; one wave per (b,t)
__global__ void geom_kernel(const float* __restrict__ hid,
                            const float* __restrict__ Gw,
                            const float* __restrict__ Gb,
                            float* __restrict__ geo)
{
    const int wid  = (blockIdx.x * blockDim.x + threadIdx.x) >> 6;
    const int lane = threadIdx.x & 63;
    if (wid >= RB * RT) return;
    const float* rowp = hid + (size_t)wid * RN;
    float g0 = 0.f, g1 = 0.f;
    #pragma unroll
    for (int j = 0; j < 8; ++j) {
        float v = rowp[lane + 64 * j];
        g0 = fmaf(v, Gw[lane + 64 * j], g0);
        g1 = fmaf(v, Gw[RN + lane + 64 * j], g1);
    }
    #pragma unroll
    for (int m = 32; m >= 1; m >>= 1) {
        g0 += __shfl_xor(g0, m);
        g1 += __shfl_xor(g1, m);
    }
    if (lane == 0) {
        geo[(size_t)wid * 2]     = g0 + Gb[0];
        geo[(size_t)wid * 2 + 1] = g1 + Gb[1];
    }
}

// per-launch init: tanh(h0) table + zero counters (ws poisoned once, never
// re-poisoned -> re-init every call; deterministic)
__global__ void init_misc(const float* __restrict__ h0,
                          float* __restrict__ tanh0,
                          unsigned* __restrict__ ctr,
                          unsigned* __restrict__ xcdctr)
{
    int i = blockIdx.x * blockDim.x + threadIdx.x;
    if (i < RN) tanh0[i] = tanhf(h0[i]);
    if (i < RB * 32) ctr[i] = 0u;
    if (i < 8) xcdctr[i] = 0u;
}

extern "C" void kernel_launch(void* const* d_in, const int* in_sizes, int n_in,
                              void* d_out, int out_size, void* d_ws, size_t ws_size,
                              hipStream_t stream)
{
    const float* h0 = (const float*)d_in[0];
    const float* X  = (const float*)d_in[1];
    const float* W  = (const float*)d_in[2];
    const float* Gw = (const float*)d_in[3];
    const float* Gb = (const float*)d_in[4];

    float* outH = (float*)d_out;
    float* geo  = outH + (size_t)RB * RT * RN;

    float*    tanh0  = (float*)d_ws;                  // 512 f32
    unsigned* ctr    = (unsigned*)d_ws + RN;          // 64*32 u32
    unsigned* xcdctr = ctr + RB * 32;                 // 8 u32
    uint4*    Wpk    = (uint4*)(((uintptr_t)(xcdctr + 8) + 15) & ~(uintptr_t)15);

    (void)hipFuncSetAttribute((const void*)rnn_step_kernel,
                              hipFuncAttributeMaxDynamicSharedMemorySize, SMEM_BYTES);

    pack_w<<<64, 512, 0, stream>>>(W, Wpk);
    init_misc<<<8, 512, 0, stream>>>(h0, tanh0, ctr, xcdctr);

    void* kargs[] = { (void*)&h0, (void*)&X, (void*)&Wpk, (void*)&tanh0,
                      (void*)&outH, (void*)&ctr, (void*)&xcdctr };
    (void)hipLaunchCooperativeKernel(rnn_step_kernel, dim3(256), dim3(512),
                                     kargs, SMEM_BYTES, stream);

    geom_kernel<<<(RB * RT * 64 + 255) / 256, 256, 0, stream>>>(outH, Gw, Gb, geo);
}